// Round 1
// baseline (436.653 us; speedup 1.0000x reference)
//
#include <hip/hip_runtime.h>

// NormalizedCrossEntropy: logits [8192,10000] f32, targets [8192] int32 -> scalar f32
//   ce_i    = lse_i - logits_i[t_i]
//   sum_ce  = C*lse_i - sum_k logits_ik
//   out     = mean_i( ce_i / (sum_ce_i + 1e-8) )

#define NB_ROWS 8192
#define NC_COLS 10000
#define NC_VEC4 (NC_COLS / 4)   // 2500, exact
#define EPSV    1e-8f

__global__ __launch_bounds__(256) void nce_row_kernel(const float* __restrict__ logits,
                                                      const int* __restrict__ targets,
                                                      float* __restrict__ row_ratio) {
    const int row = blockIdx.x;
    const int tid = threadIdx.x;
    const float* __restrict__ rp = logits + (size_t)row * NC_COLS;
    const float4* __restrict__ rp4 = reinterpret_cast<const float4*>(rp);

    float sum_exp = 0.0f;
    float sum_x   = 0.0f;

    // 2500 float4 / 256 threads -> ~10 iterations, fully coalesced 16B/lane
    for (int i = tid; i < NC_VEC4; i += 256) {
        float4 v = rp4[i];
        sum_x   += (v.x + v.y) + (v.z + v.w);
        sum_exp += (__expf(v.x) + __expf(v.y)) + (__expf(v.z) + __expf(v.w));
    }

    // wave64 butterfly-free down-reduce
    #pragma unroll
    for (int off = 32; off > 0; off >>= 1) {
        sum_exp += __shfl_down(sum_exp, off);
        sum_x   += __shfl_down(sum_x,   off);
    }

    __shared__ float s_exp[4];
    __shared__ float s_x[4];
    const int wave = tid >> 6;
    if ((tid & 63) == 0) { s_exp[wave] = sum_exp; s_x[wave] = sum_x; }
    __syncthreads();

    if (tid == 0) {
        const float se  = (s_exp[0] + s_exp[1]) + (s_exp[2] + s_exp[3]);
        const float sx  = (s_x[0]   + s_x[1])   + (s_x[2]   + s_x[3]);
        const float lse = __logf(se);
        const float tgt = rp[targets[row]];   // one cached scalar read per row
        const float ce  = lse - tgt;
        const float sum_ce = (float)NC_COLS * lse - sx;
        row_ratio[row] = ce / (sum_ce + EPSV);
    }
}

__global__ __launch_bounds__(256) void nce_reduce_kernel(const float* __restrict__ row_ratio,
                                                         float* __restrict__ out) {
    const int tid = threadIdx.x;
    float s = 0.0f;
    for (int i = tid; i < NB_ROWS; i += 256) s += row_ratio[i];

    #pragma unroll
    for (int off = 32; off > 0; off >>= 1) s += __shfl_down(s, off);

    __shared__ float sw[4];
    if ((tid & 63) == 0) sw[tid >> 6] = s;
    __syncthreads();

    if (tid == 0) out[0] = ((sw[0] + sw[1]) + (sw[2] + sw[3])) * (1.0f / (float)NB_ROWS);
}

extern "C" void kernel_launch(void* const* d_in, const int* in_sizes, int n_in,
                              void* d_out, int out_size, void* d_ws, size_t ws_size,
                              hipStream_t stream) {
    const float* logits  = (const float*)d_in[0];
    const int*   targets = (const int*)d_in[1];
    float* out = (float*)d_out;
    float* row_ratio = (float*)d_ws;   // 8192 * 4 B = 32 KiB scratch

    nce_row_kernel<<<NB_ROWS, 256, 0, stream>>>(logits, targets, row_ratio);
    nce_reduce_kernel<<<1, 256, 0, stream>>>(row_ratio, out);
}

// Round 7
// 427.649 us; speedup vs baseline: 1.0211x; 1.0211x over previous
//
#include <hip/hip_runtime.h>

// NormalizedCrossEntropy: logits [8192,10000] f32, targets [8192] int32 -> scalar f32
//   ce_i    = lse_i - logits_i[t_i]
//   sum_ce_i= C*lse_i - sum_k logits_ik
//   out     = mean_i( ce_i / (sum_ce_i + 1e-8) )
//
// Memory-bound: 327.7 MB read-once -> floor ~52us @ 6.3 TB/s.
// Row kernel: 1 block (256 thr) per row, fully-unrolled 10x float4 loads
// (2500 vec4/row), predicated tail, dual accumulators for ILP.

#define NB_ROWS 8192
#define NC_COLS 10000
#define NC_VEC4 (NC_COLS / 4)   // 2500, exact
#define EPSV    1e-8f

__global__ __launch_bounds__(256) void nce_row_kernel(const float* __restrict__ logits,
                                                      const int* __restrict__ targets,
                                                      float* __restrict__ row_ratio) {
    const int row = blockIdx.x;
    const int tid = threadIdx.x;
    const float* __restrict__ rp = logits + (size_t)row * NC_COLS;
    const float4* __restrict__ rp4 = reinterpret_cast<const float4*>(rp);

    float se0 = 0.0f, se1 = 0.0f;   // sum of exp
    float sx0 = 0.0f, sx1 = 0.0f;   // sum of x

    // 2500 = 9*256 + 196. Compile-time trip count so all independent
    // global_load_dwordx4 can issue before the exp chains consume them.
    #pragma unroll
    for (int k = 0; k < 10; ++k) {
        const int idx = tid + (k << 8);
        if (idx < NC_VEC4) {
            const float4 v = rp4[idx];
            if (k & 1) {
                sx1 += (v.x + v.y) + (v.z + v.w);
                se1 += (__expf(v.x) + __expf(v.y)) + (__expf(v.z) + __expf(v.w));
            } else {
                sx0 += (v.x + v.y) + (v.z + v.w);
                se0 += (__expf(v.x) + __expf(v.y)) + (__expf(v.z) + __expf(v.w));
            }
        }
    }

    float sum_exp = se0 + se1;
    float sum_x   = sx0 + sx1;

    #pragma unroll
    for (int off = 32; off > 0; off >>= 1) {
        sum_exp += __shfl_down(sum_exp, off);
        sum_x   += __shfl_down(sum_x,   off);
    }

    __shared__ float s_exp[4];
    __shared__ float s_x[4];
    const int wave = tid >> 6;
    if ((tid & 63) == 0) { s_exp[wave] = sum_exp; s_x[wave] = sum_x; }
    __syncthreads();

    if (tid == 0) {
        const float se  = (s_exp[0] + s_exp[1]) + (s_exp[2] + s_exp[3]);
        const float sx  = (s_x[0]   + s_x[1])   + (s_x[2]   + s_x[3]);
        const float lse = __logf(se);
        const float tgt = rp[targets[row]];   // one cached scalar read per row
        const float ce  = lse - tgt;
        const float sum_ce = (float)NC_COLS * lse - sx;
        row_ratio[row] = ce / (sum_ce + EPSV);
    }
}

__global__ __launch_bounds__(256) void nce_reduce_kernel(const float* __restrict__ row_ratio,
                                                         float* __restrict__ out) {
    const int tid = threadIdx.x;
    float s = 0.0f;
    #pragma unroll
    for (int k = 0; k < NB_ROWS / 256; ++k) s += row_ratio[tid + (k << 8)];

    #pragma unroll
    for (int off = 32; off > 0; off >>= 1) s += __shfl_down(s, off);

    __shared__ float sw[4];
    if ((tid & 63) == 0) sw[tid >> 6] = s;
    __syncthreads();

    if (tid == 0) out[0] = ((sw[0] + sw[1]) + (sw[2] + sw[3])) * (1.0f / (float)NB_ROWS);
}

extern "C" void kernel_launch(void* const* d_in, const int* in_sizes, int n_in,
                              void* d_out, int out_size, void* d_ws, size_t ws_size,
                              hipStream_t stream) {
    const float* logits  = (const float*)d_in[0];
    const int*   targets = (const int*)d_in[1];
    float* out = (float*)d_out;
    float* row_ratio = (float*)d_ws;   // 8192 * 4 B = 32 KiB scratch

    nce_row_kernel<<<NB_ROWS, 256, 0, stream>>>(logits, targets, row_ratio);
    nce_reduce_kernel<<<1, 256, 0, stream>>>(row_ratio, out);
}